// Round 6
// baseline (238.249 us; speedup 1.0000x reference)
//
#include <hip/hip_runtime.h>
#include <math.h>

namespace {

constexpr int kRays    = 65536;
constexpr int kSamples = 128;
constexpr float kEpsilonBig = 1.0e10f;   // EPSILON in the reference

// grid: 2048 blocks x 256 threads = 8192 waves; each wave handles 8 rays
constexpr int kWaves       = 8192;
constexpr int kRaysPerWave = kRays / kWaves;  // 8

// d_out layout: outputs concatenated flat in reference return order
constexpr int OFF_RGB   = 0;                          // (kRays, 3)
constexpr int OFF_DEPTH = OFF_RGB + kRays * 3;        // (kRays,)
constexpr int OFF_W     = OFF_DEPTH + kRays;          // (kRays, 128)
constexpr int OFF_M     = OFF_W + kRays * kSamples;   // (kRays, 128)
constexpr int OFF_ACC   = OFF_M + kRays * kSamples;   // (kRays,)
constexpr int OFF_DISP  = OFF_ACC + kRays;            // (kRays,)

// ---- DPP cross-lane primitives (VALU pipe — no ds_bpermute, no lgkmcnt) ----
#define DPP_ADD_F32(v, ctrl, rmask)                                         \
  (v) += __int_as_float(__builtin_amdgcn_update_dpp(                        \
      0, __float_as_int(v), (ctrl), (rmask), 0xf, true))

// full 64-lane inclusive sum scan; lane 63 ends with the wave total
#define DPP_REDUCE_F32(v)                                                   \
  do {                                                                      \
    DPP_ADD_F32(v, 0x111, 0xf); /* row_shr:1  */                            \
    DPP_ADD_F32(v, 0x112, 0xf); /* row_shr:2  */                            \
    DPP_ADD_F32(v, 0x114, 0xf); /* row_shr:4  */                            \
    DPP_ADD_F32(v, 0x118, 0xf); /* row_shr:8  */                            \
    DPP_ADD_F32(v, 0x142, 0xa); /* row_bcast:15 -> rows 1,3 */              \
    DPP_ADD_F32(v, 0x143, 0xc); /* row_bcast:31 -> rows 2,3 */              \
  } while (0)

// f64 product step: invalid/masked lanes keep old = 1.0 (multiplicative identity)
#define DPP_MUL_F64(p, ctrl, rmask)                                         \
  do {                                                                      \
    unsigned long long _b = (unsigned long long)__double_as_longlong(p);    \
    int _lo = __builtin_amdgcn_update_dpp(                                  \
        0x00000000, (int)(unsigned)(_b & 0xffffffffull), (ctrl), (rmask),   \
        0xf, false);                                                        \
    int _hi = __builtin_amdgcn_update_dpp(                                  \
        0x3ff00000, (int)(unsigned)(_b >> 32), (ctrl), (rmask),             \
        0xf, false);                                                        \
    (p) *= __longlong_as_double(                                            \
        (long long)(((unsigned long long)(unsigned)_hi << 32) |             \
                    (unsigned)_lo));                                        \
  } while (0)

__global__ __launch_bounds__(256) void volume_render_kernel(
    const float* __restrict__ rf,     // (kRays, 128, 4)
    const float* __restrict__ depth,  // (kRays, 128)
    const float* __restrict__ rd,     // (kRays, 3)
    float* __restrict__ out)
{
  const int lane = threadIdx.x & 63;
  const int wid  = (blockIdx.x * blockDim.x + threadIdx.x) >> 6;  // 0..8191

  const float4* rf4  = reinterpret_cast<const float4*>(rf);
  const float2* dep2 = reinterpret_cast<const float2*>(depth);
  float2* outw = reinterpret_cast<float2*>(out + OFF_W);
  float2* outm = reinterpret_cast<float2*>(out + OFF_M);

  // ---- prologue: load ray 0 of this wave (pair-blocked: lane owns 2i,2i+1) ----
  float4 a0 = rf4[wid * kSamples + 2 * lane];
  float4 a1 = rf4[wid * kSamples + 2 * lane + 1];
  float2 ad = dep2[wid * 64 + lane];

#pragma unroll
  for (int i = 0; i < kRaysPerWave; ++i) {
    const int cray = wid + i * kWaves;        // grid-stride ray assignment

    // ---- prefetch next ray's data (2-deep software pipeline) ----
    float4 b0 = {}, b1 = {};
    float2 bd = {};
    if (i + 1 < kRaysPerWave) {
      const int nray = cray + kWaves;
      b0 = rf4[nray * kSamples + 2 * lane];
      b1 = rf4[nray * kSamples + 2 * lane + 1];
      bd = dep2[nray * 64 + lane];
    }

    // ---- compute for cray using a0, a1, ad ----
    const int uray = __builtin_amdgcn_readfirstlane(cray);
    const float rx = rd[uray * 3 + 0];
    const float ry = rd[uray * 3 + 1];
    const float rz = rd[uray * 3 + 2];
    const float nrm = sqrtf(rx * rx + ry * ry + rz * rz);

    // deltas: even-sample delta lane-local; odd needs 1 neighbor shfl
    const float dnext  = __shfl_down(ad.x, 1);           // depth[2i+2]
    const float delta0 = (ad.y - ad.x) * nrm;
    const float delta1 = (lane == 63) ? kEpsilonBig * nrm : (dnext - ad.y) * nrm;

    // alpha (f32, ~1 ulp vs np's f32 exp)
    const float alpha0 = 1.0f - expf(-fmaxf(a0.w, 0.0f) * delta0);
    const float alpha1 = 1.0f - expf(-fmaxf(a1.w, 0.0f) * delta1);

    // t_i rounded to f32 exactly like the reference, then promoted; the f64
    // scan multiplies the SAME f32 factors the reference multiplies
    const float t0f = (1.0f - alpha0) + 1e-10f;
    const float t1f = (1.0f - alpha1) + 1e-10f;

    // exclusive cumprod: local pair product + 64-lane DPP scan (f64)
    double P = (double)t0f * (double)t1f;                // lane product
    DPP_MUL_F64(P, 0x111, 0xf);  // row_shr:1
    DPP_MUL_F64(P, 0x112, 0xf);  // row_shr:2
    DPP_MUL_F64(P, 0x114, 0xf);  // row_shr:4
    DPP_MUL_F64(P, 0x118, 0xf);  // row_shr:8
    DPP_MUL_F64(P, 0x142, 0xa);  // row_bcast:15 -> rows 1,3
    DPP_MUL_F64(P, 0x143, 0xc);  // row_bcast:31 -> rows 2,3

    double e = __shfl_up(P, 1);                          // exclusive shift
    if (lane == 0) e = 1.0;
    const double T0 = e;                                 // T at sample 2i
    const double T1 = e * (double)t0f;                   // T at sample 2i+1

    const float w0 = (float)(T0 * (double)alpha0);
    const float w1 = (float)(T1 * (double)alpha1);

    const double thr = (double)0.001f;  // numpy compares vs f32-cast 0.001

    // full-size outputs (float2, coalesced)
    outw[cray * 64 + lane] = make_float2(w0, w1);
    outm[cray * 64 + lane] =
        make_float2((T0 > thr) ? 1.0f : 0.0f, (T1 > thr) ? 1.0f : 0.0f);

    // wave reductions via DPP (result in lane 63)
    float r   = w0 * a0.x + w1 * a1.x;
    float g   = w0 * a0.y + w1 * a1.y;
    float b   = w0 * a0.z + w1 * a1.z;
    float acc = w0 + w1;
    float dm  = w0 * ad.x + w1 * ad.y;
    DPP_REDUCE_F32(r);
    DPP_REDUCE_F32(g);
    DPP_REDUCE_F32(b);
    DPP_REDUCE_F32(acc);
    DPP_REDUCE_F32(dm);

    if (lane == 63) {
      out[OFF_RGB + cray * 3 + 0] = r;
      out[OFF_RGB + cray * 3 + 1] = g;
      out[OFF_RGB + cray * 3 + 2] = b;
      out[OFF_DEPTH + cray] = dm;
      out[OFF_ACC + cray]   = acc;
      const float q = dm / acc;             // may be NaN (0/0)
      float disp;
      if (isnan(q)) {
        disp = 0.0f;                        // jnp.maximum propagates NaN -> where() zeroes it
      } else {
        disp = 1.0f / fmaxf(1e-10f, q);     // matches reference
      }
      out[OFF_DISP + cray] = disp;
    }

    // ---- rotate pipeline registers ----
    a0 = b0; a1 = b1; ad = bd;
  }
}

}  // namespace

extern "C" void kernel_launch(void* const* d_in, const int* in_sizes, int n_in,
                              void* d_out, int out_size, void* d_ws, size_t ws_size,
                              hipStream_t stream) {
  const float* rf    = (const float*)d_in[0];   // radiance_field (65536,128,4)
  const float* depth = (const float*)d_in[1];   // depth_values   (65536,128)
  const float* rd    = (const float*)d_in[2];   // ray_directions (65536,3)
  float* out = (float*)d_out;

  // 8192 waves, 8 rays each, grid-stride: 2048 blocks of 256 threads
  const int blocks = (kWaves * 64) / 256;       // 2048
  volume_render_kernel<<<blocks, 256, 0, stream>>>(rf, depth, rd, out);
}